// Round 1
// baseline (541.886 us; speedup 1.0000x reference)
//
#include <hip/hip_runtime.h>
#include <hip/hip_bf16.h>
#include <stdint.h>

typedef __attribute__((ext_vector_type(8))) short short8;
typedef __attribute__((ext_vector_type(4))) short short4v;
typedef __attribute__((ext_vector_type(4))) float f32x4;

#define LSEQ 4096
#define DMODEL 1024
#define NHEAD 8
#define HDIM 128
#define MTOT 8192
#define NQKV 3072

__device__ __forceinline__ unsigned short f2bf(float f){
  unsigned u = __float_as_uint(f);
  u += 0x7fffu + ((u >> 16) & 1u);
  return (unsigned short)(u >> 16);
}
__device__ __forceinline__ float bf2f(unsigned short h){
  return __uint_as_float(((unsigned)h) << 16);
}

typedef const __attribute__((address_space(1))) void* gas_ptr;
typedef __attribute__((address_space(3))) void* las_ptr;
__device__ __forceinline__ void gload_lds16(const void* g, void* l){
  __builtin_amdgcn_global_load_lds((gas_ptr)(uintptr_t)g,
                                   (las_ptr)(unsigned)(uintptr_t)l, 16, 0, 0);
}

// ---------------- fp32 -> bf16 cast (8 elems/thread) ----------------
__global__ __launch_bounds__(256) void k_cvt(const float* __restrict__ in,
                                             unsigned short* __restrict__ out, int n8){
  int i = blockIdx.x*256 + threadIdx.x;
  if (i >= n8) return;
  const float4* p = (const float4*)in + (size_t)i*2;
  float4 a = p[0], b = p[1];
  short8 r;
  r[0]=(short)f2bf(a.x); r[1]=(short)f2bf(a.y); r[2]=(short)f2bf(a.z); r[3]=(short)f2bf(a.w);
  r[4]=(short)f2bf(b.x); r[5]=(short)f2bf(b.y); r[6]=(short)f2bf(b.z); r[7]=(short)f2bf(b.w);
  *(short8*)(out + (size_t)i*8) = r;
}

// ---------------- fp32 [R][C] -> bf16 transposed [C][R] ----------------
__global__ __launch_bounds__(256) void k_transpose_cvt(const float* __restrict__ in,
                                                       unsigned short* __restrict__ out,
                                                       int R, int C){
  __shared__ unsigned short tile[32][33];
  int c0 = blockIdx.x*32, r0 = blockIdx.y*32;
  int tx = threadIdx.x & 31, ty = threadIdx.x >> 5;   // 32 x 8
  #pragma unroll
  for (int i=0;i<32;i+=8)
    tile[ty+i][tx] = f2bf(in[(size_t)(r0+ty+i)*C + c0+tx]);
  __syncthreads();
  #pragma unroll
  for (int i=0;i<32;i+=8)
    out[(size_t)(c0+ty+i)*R + r0+tx] = tile[tx][ty+i];
}

// ---------------- bf16 GEMM: C[M][N] = A[M][K] * Bt[N][K]^T + bias ----------------
// 128x128 tile, BK=64, 4 waves (2x2), 16x16x32 MFMA, global_load_lds staging
// with XOR-swizzled LDS (pre-swizzled global source).
template<int OUT_BF16>
__global__ __launch_bounds__(256) void k_gemm_bt(const unsigned short* __restrict__ A,
                                                 const unsigned short* __restrict__ Bt,
                                                 const float* __restrict__ bias,
                                                 void* __restrict__ Cout,
                                                 int M, int N, int K){
  __shared__ unsigned short As[128*64];
  __shared__ unsigned short Bs[128*64];
  int tid = threadIdx.x, lane = tid & 63, wave = tid >> 6;
  int wm = wave >> 1, wn = wave & 1;
  int m0 = blockIdx.y*128, n0 = blockIdx.x*128;
  f32x4 zero = {0.f,0.f,0.f,0.f};
  f32x4 acc[4][4];
  #pragma unroll
  for (int mi=0;mi<4;++mi)
    #pragma unroll
    for (int ni=0;ni<4;++ni) acc[mi][ni] = zero;

  int srow = lane >> 3;          // row within 8-row chunk (rows are 128B)
  int soffb = (lane & 7) * 16;   // byte offset within row
  int scol = (soffb ^ (srow << 4)) >> 1;   // pre-swizzled source column (elems)
  int cg = lane >> 4, cl = lane & 15;

  int nkt = K >> 6;
  for (int kt = 0; kt < nkt; ++kt){
    if (kt) __syncthreads();
    int kbase = kt*64;
    #pragma unroll
    for (int j=0;j<4;++j){
      int ch = wave*4 + j;           // 16 chunks of 1KB (8 rows each)
      int row = ch*8 + srow;
      gload_lds16(A  + (size_t)(m0+row)*K + kbase + scol, (char*)As + ch*1024);
      gload_lds16(Bt + (size_t)(n0+row)*K + kbase + scol, (char*)Bs + ch*1024);
    }
    __syncthreads();

    short8 af[4][2], bf[4][2];
    #pragma unroll
    for (int mi=0;mi<4;++mi){
      int row = wm*64 + mi*16 + cl;
      int key = (row & 7) << 4;
      #pragma unroll
      for (int kk=0;kk<2;++kk)
        af[mi][kk] = *(const short8*)((const char*)As + row*128 + ((kk*64 + cg*16) ^ key));
    }
    #pragma unroll
    for (int ni=0;ni<4;++ni){
      int row = wn*64 + ni*16 + cl;
      int key = (row & 7) << 4;
      #pragma unroll
      for (int kk=0;kk<2;++kk)
        bf[ni][kk] = *(const short8*)((const char*)Bs + row*128 + ((kk*64 + cg*16) ^ key));
    }
    #pragma unroll
    for (int kk=0;kk<2;++kk)
      #pragma unroll
      for (int mi=0;mi<4;++mi)
        #pragma unroll
        for (int ni=0;ni<4;++ni)
          acc[mi][ni] = __builtin_amdgcn_mfma_f32_16x16x32_bf16(af[mi][kk], bf[ni][kk], acc[mi][ni], 0,0,0);
  }

  #pragma unroll
  for (int ni=0;ni<4;++ni){
    int col = n0 + wn*64 + ni*16 + cl;
    float bv = bias[col];
    #pragma unroll
    for (int mi=0;mi<4;++mi){
      int r = m0 + wm*64 + mi*16 + cg*4;
      #pragma unroll
      for (int i=0;i<4;++i){
        float v = acc[mi][ni][i] + bv;
        if (OUT_BF16) ((unsigned short*)Cout)[(size_t)(r+i)*N + col] = f2bf(v);
        else          ((float*)Cout)[(size_t)(r+i)*N + col] = v;
      }
    }
  }
}

// ---------------- fused RMSNorm(q,k) + interleaved RoPE, in-place on bf16 qkv ----------------
__global__ __launch_bounds__(256) void k_norm_rope(unsigned short* __restrict__ qkv,
                                                   const float* __restrict__ fcos,
                                                   const float* __restrict__ fsin,
                                                   const float* __restrict__ gq,
                                                   const float* __restrict__ gk){
  int bl = blockIdx.x;            // b*4096 + l
  int l = bl & (LSEQ-1);
  int t = threadIdx.x;
  unsigned short* row = qkv + (size_t)bl * NQKV;
  int d0 = t*4;
  short4v qv = *(short4v*)(row + d0);
  short4v kv = *(short4v*)(row + DMODEL + d0);
  float q[4], k[4];
  #pragma unroll
  for (int j=0;j<4;++j){ q[j] = bf2f((unsigned short)qv[j]); k[j] = bf2f((unsigned short)kv[j]); }
  float sq = q[0]*q[0]+q[1]*q[1]+q[2]*q[2]+q[3]*q[3];
  float sk = k[0]*k[0]+k[1]*k[1]+k[2]*k[2]+k[3]*k[3];
  #pragma unroll
  for (int o=32;o;o>>=1){ sq += __shfl_xor(sq,o); sk += __shfl_xor(sk,o); }
  __shared__ float red[8];
  int lane = t & 63, wv = t >> 6;
  if (!lane){ red[wv] = sq; red[4+wv] = sk; }
  __syncthreads();
  sq = red[0]+red[1]+red[2]+red[3];
  sk = red[4]+red[5]+red[6]+red[7];
  float rq = rsqrtf(sq*(1.f/1024.f) + 1e-6f);
  float rk = rsqrtf(sk*(1.f/1024.f) + 1e-6f);
  int hd = d0 & (HDIM-1);
  int fi = (l << 6) + (hd >> 1);
  float c0 = fcos[fi], s0 = fsin[fi], c1 = fcos[fi+1], s1 = fsin[fi+1];
  {
    float x1 = q[0]*rq*gq[d0],   x2 = q[1]*rq*gq[d0+1];
    float x3 = q[2]*rq*gq[d0+2], x4 = q[3]*rq*gq[d0+3];
    short4v qo;
    qo[0]=(short)f2bf(x1*c0 - x2*s0); qo[1]=(short)f2bf(x1*s0 + x2*c0);
    qo[2]=(short)f2bf(x3*c1 - x4*s1); qo[3]=(short)f2bf(x3*s1 + x4*c1);
    *(short4v*)(row + d0) = qo;
  }
  {
    float x1 = k[0]*rk*gk[d0],   x2 = k[1]*rk*gk[d0+1];
    float x3 = k[2]*rk*gk[d0+2], x4 = k[3]*rk*gk[d0+3];
    short4v ko;
    ko[0]=(short)f2bf(x1*c0 - x2*s0); ko[1]=(short)f2bf(x1*s0 + x2*c0);
    ko[2]=(short)f2bf(x3*c1 - x4*s1); ko[3]=(short)f2bf(x3*s1 + x4*c1);
    *(short4v*)(row + DMODEL + d0) = ko;
  }
}

// ---------------- flash attention: 4 waves x 16 q-rows, KVBLK=64 ----------------
__global__ __launch_bounds__(256) void k_attn(const unsigned short* __restrict__ qkv,
                                              unsigned short* __restrict__ o){
  __shared__ unsigned short Ks[64*128];       // xor-swizzled content, linear layout
  __shared__ unsigned short VT[128*72];       // V transposed, padded stride 72
  __shared__ unsigned short Ps[4][16*72];     // per-wave P, padded stride 72
  int bh = blockIdx.y; int b = bh >> 3, h = bh & 7;
  int q0 = blockIdx.x * 64;
  int tid = threadIdx.x, lane = tid & 63, wave = tid >> 6;
  int cg = lane >> 4, cl = lane & 15;
  const unsigned short* base = qkv + (size_t)b*LSEQ*NQKV + h*HDIM;
  const unsigned short* kgl = base + DMODEL;
  const unsigned short* vgl = base + 2*DMODEL;

  short8 qf[4];
  {
    const unsigned short* qr = base + (size_t)(q0 + wave*16 + cl)*NQKV;
    #pragma unroll
    for (int kk=0;kk<4;++kk) qf[kk] = *(const short8*)(qr + kk*32 + cg*8);
  }
  float mrow[4], lrow[4];
  f32x4 zero = {0.f,0.f,0.f,0.f};
  f32x4 accO[8];
  #pragma unroll
  for (int i=0;i<4;++i){ mrow[i] = -1e30f; lrow[i] = 0.f; }
  #pragma unroll
  for (int dt=0;dt<8;++dt) accO[dt] = zero;
  const float scale = 0.08838834764831843f;   // 1/sqrt(128)

  for (int kv0 = 0; kv0 < LSEQ; kv0 += 64){
    if (kv0) __syncthreads();
    // stage K tile (64 rows x 128) via global_load_lds, pre-swizzled source
    #pragma unroll
    for (int j=0;j<4;++j){
      int ch = wave*4 + j;              // 16 chunks of 1KB (4 rows of 256B)
      int row = ch*4 + cg;
      int srcb = (cl*16) ^ ((row & 7) << 4);
      gload_lds16(kgl + (size_t)(kv0+row)*NQKV + (srcb >> 1), (char*)Ks + ch*1024);
    }
    // stage V transposed (reg-staged): wave handles 32-col d-block for all 64 kv rows
    {
      const unsigned short* vr = vgl + (size_t)(kv0+lane)*NQKV + wave*32;
      #pragma unroll
      for (int i=0;i<4;++i){
        short8 vv = *(const short8*)(vr + i*8);
        int d0 = wave*32 + i*8;
        #pragma unroll
        for (int j=0;j<8;++j) VT[(d0+j)*72 + lane] = (unsigned short)vv[j];
      }
    }
    __syncthreads();

    // QK^T : S[16 q][64 kv] per wave
    f32x4 s[4];
    #pragma unroll
    for (int nt=0;nt<4;++nt){
      f32x4 a = zero;
      int row = nt*16 + cl;
      int key = (row & 7) << 4;
      #pragma unroll
      for (int kk=0;kk<4;++kk){
        short8 kf = *(const short8*)((const char*)Ks + row*256 + ((kk*64 + cg*16) ^ key));
        a = __builtin_amdgcn_mfma_f32_16x16x32_bf16(qf[kk], kf, a, 0,0,0);
      }
      s[nt] = a * scale;
    }
    // online softmax per row (rows cg*4+i, reduce across the 16 cl lanes)
    float fac[4];
    #pragma unroll
    for (int i=0;i<4;++i){
      float mx = fmaxf(fmaxf(s[0][i],s[1][i]), fmaxf(s[2][i],s[3][i]));
      mx = fmaxf(mx, __shfl_xor(mx,1));
      mx = fmaxf(mx, __shfl_xor(mx,2));
      mx = fmaxf(mx, __shfl_xor(mx,4));
      mx = fmaxf(mx, __shfl_xor(mx,8));
      float mn = fmaxf(mrow[i], mx);
      float sum = 0.f;
      #pragma unroll
      for (int nt=0;nt<4;++nt){ float p = __expf(s[nt][i]-mn); s[nt][i]=p; sum += p; }
      sum += __shfl_xor(sum,1); sum += __shfl_xor(sum,2);
      sum += __shfl_xor(sum,4); sum += __shfl_xor(sum,8);
      float f = __expf(mrow[i]-mn);
      lrow[i] = lrow[i]*f + sum;
      mrow[i] = mn;
      fac[i] = f;
    }
    #pragma unroll
    for (int dt=0;dt<8;++dt){
      f32x4 t = accO[dt];
      t[0]*=fac[0]; t[1]*=fac[1]; t[2]*=fac[2]; t[3]*=fac[3];
      accO[dt] = t;
    }
    // P -> bf16 -> per-wave LDS (A-frag layout for PV)
    unsigned short* pw = &Ps[wave][0];
    #pragma unroll
    for (int nt=0;nt<4;++nt)
      #pragma unroll
      for (int i=0;i<4;++i)
        pw[(cg*4+i)*72 + nt*16 + cl] = f2bf(s[nt][i]);
    // PV : O[16 q][128 d] += P[16][64] * V[64][128]
    #pragma unroll
    for (int kk=0;kk<2;++kk){
      short8 pa = *(const short8*)((const char*)pw + (cl*72 + kk*32 + cg*8)*2);
      #pragma unroll
      for (int dt=0;dt<8;++dt){
        short8 vf = *(const short8*)((const char*)VT + ((dt*16+cl)*72 + kk*32 + cg*8)*2);
        accO[dt] = __builtin_amdgcn_mfma_f32_16x16x32_bf16(pa, vf, accO[dt], 0,0,0);
      }
    }
  }
  // epilogue: o[b][l][h*128+d] bf16
  size_t orow = (size_t)(b*LSEQ + q0 + wave*16 + cg*4);
  #pragma unroll
  for (int dt=0;dt<8;++dt)
    #pragma unroll
    for (int i=0;i<4;++i){
      float v = accO[dt][i] / lrow[i];
      o[(orow+i)*DMODEL + h*HDIM + dt*16 + cl] = f2bf(v);
    }
}

extern "C" void kernel_launch(void* const* d_in, const int* in_sizes, int n_in,
                              void* d_out, int out_size, void* d_ws, size_t ws_size,
                              hipStream_t stream) {
  const float* x    = (const float*)d_in[0];
  const float* fcos = (const float*)d_in[1];
  const float* fsin = (const float*)d_in[2];
  const float* wqkv = (const float*)d_in[3];
  const float* bqkv = (const float*)d_in[4];
  const float* gq   = (const float*)d_in[5];
  const float* gk   = (const float*)d_in[6];
  const float* wout = (const float*)d_in[7];
  const float* bout = (const float*)d_in[8];
  float* out = (float*)d_out;

  char* ws = (char*)d_ws;
  unsigned short* xb    = (unsigned short*)(ws);                       // 16MB: x bf16
  unsigned short* qkv   = (unsigned short*)(ws + (16ull<<20));         // 48MB: qkv bf16
  unsigned short* ob    = (unsigned short*)(ws + (64ull<<20));         // 16MB: o bf16
  unsigned short* wqkvT = (unsigned short*)(ws + (80ull<<20));         // 6MB
  unsigned short* woutT = (unsigned short*)(ws + (86ull<<20));         // 2MB

  k_cvt<<<4096, 256, 0, stream>>>(x, xb, (MTOT*DMODEL)/8);
  k_transpose_cvt<<<dim3(96,32), 256, 0, stream>>>(wqkv, wqkvT, DMODEL, NQKV);
  k_transpose_cvt<<<dim3(32,32), 256, 0, stream>>>(wout, woutT, DMODEL, DMODEL);
  k_gemm_bt<1><<<dim3(NQKV/128, MTOT/128), 256, 0, stream>>>(xb, wqkvT, bqkv, qkv, MTOT, NQKV, DMODEL);
  k_norm_rope<<<MTOT, 256, 0, stream>>>(qkv, fcos, fsin, gq, gk);
  k_attn<<<dim3(LSEQ/64, 16), 256, 0, stream>>>(qkv, ob);
  k_gemm_bt<0><<<dim3(DMODEL/128, MTOT/128), 256, 0, stream>>>(ob, woutT, bout, out, MTOT, DMODEL, DMODEL);
}

// Round 3
// 347.548 us; speedup vs baseline: 1.5592x; 1.5592x over previous
//
#include <hip/hip_runtime.h>
#include <hip/hip_bf16.h>
#include <stdint.h>

typedef __attribute__((ext_vector_type(8))) short short8;
typedef __attribute__((ext_vector_type(4))) short short4v;
typedef __attribute__((ext_vector_type(4))) float f32x4;

#define LSEQ 4096
#define DMODEL 1024
#define NHEAD 8
#define HDIM 128
#define MTOT 8192
#define NQKV 3072

__device__ __forceinline__ unsigned short f2bf(float f){
  unsigned u = __float_as_uint(f);
  u += 0x7fffu + ((u >> 16) & 1u);
  return (unsigned short)(u >> 16);
}
__device__ __forceinline__ float bf2f(unsigned short h){
  return __uint_as_float(((unsigned)h) << 16);
}

typedef const __attribute__((address_space(1))) void* gas_ptr;
typedef __attribute__((address_space(3))) void* las_ptr;
__device__ __forceinline__ void gload_lds16(const void* g, void* l){
  __builtin_amdgcn_global_load_lds((gas_ptr)(uintptr_t)g,
                                   (las_ptr)(unsigned)(uintptr_t)l, 16, 0, 0);
}

// ---------------- fp32 -> bf16 cast (8 elems/thread) ----------------
__global__ __launch_bounds__(256) void k_cvt(const float* __restrict__ in,
                                             unsigned short* __restrict__ out, int n8){
  int i = blockIdx.x*256 + threadIdx.x;
  if (i >= n8) return;
  const float4* p = (const float4*)in + (size_t)i*2;
  float4 a = p[0], b = p[1];
  short8 r;
  r[0]=(short)f2bf(a.x); r[1]=(short)f2bf(a.y); r[2]=(short)f2bf(a.z); r[3]=(short)f2bf(a.w);
  r[4]=(short)f2bf(b.x); r[5]=(short)f2bf(b.y); r[6]=(short)f2bf(b.z); r[7]=(short)f2bf(b.w);
  *(short8*)(out + (size_t)i*8) = r;
}

// ---------------- fp32 [R][C] -> bf16 transposed [C][R] ----------------
__global__ __launch_bounds__(256) void k_transpose_cvt(const float* __restrict__ in,
                                                       unsigned short* __restrict__ out,
                                                       int R, int C){
  __shared__ unsigned short tile[32][33];
  int c0 = blockIdx.x*32, r0 = blockIdx.y*32;
  int tx = threadIdx.x & 31, ty = threadIdx.x >> 5;   // 32 x 8
  #pragma unroll
  for (int i=0;i<32;i+=8)
    tile[ty+i][tx] = f2bf(in[(size_t)(r0+ty+i)*C + c0+tx]);
  __syncthreads();
  #pragma unroll
  for (int i=0;i<32;i+=8)
    out[(size_t)(c0+ty+i)*R + r0+tx] = tile[tx][ty+i];
}

// ---------------- bf16 GEMM: C[M][N] = A[M][K] * Bt[N][K]^T + bias ----------------
template<int OUT_BF16>
__global__ __launch_bounds__(256) void k_gemm_bt(const unsigned short* __restrict__ A,
                                                 const unsigned short* __restrict__ Bt,
                                                 const float* __restrict__ bias,
                                                 void* __restrict__ Cout,
                                                 int M, int N, int K){
  __shared__ unsigned short As[128*64];
  __shared__ unsigned short Bs[128*64];
  int tid = threadIdx.x, lane = tid & 63, wave = tid >> 6;
  int wm = wave >> 1, wn = wave & 1;
  int m0 = blockIdx.y*128, n0 = blockIdx.x*128;
  f32x4 zero = {0.f,0.f,0.f,0.f};
  f32x4 acc[4][4];
  #pragma unroll
  for (int mi=0;mi<4;++mi)
    #pragma unroll
    for (int ni=0;ni<4;++ni) acc[mi][ni] = zero;

  int srow = lane >> 3;
  int soffb = (lane & 7) * 16;
  int scol = (soffb ^ (srow << 4)) >> 1;
  int cg = lane >> 4, cl = lane & 15;

  int nkt = K >> 6;
  for (int kt = 0; kt < nkt; ++kt){
    if (kt) __syncthreads();
    int kbase = kt*64;
    #pragma unroll
    for (int j=0;j<4;++j){
      int ch = wave*4 + j;
      int row = ch*8 + srow;
      gload_lds16(A  + (size_t)(m0+row)*K + kbase + scol, (char*)As + ch*1024);
      gload_lds16(Bt + (size_t)(n0+row)*K + kbase + scol, (char*)Bs + ch*1024);
    }
    __syncthreads();

    short8 af[4][2], bf[4][2];
    #pragma unroll
    for (int mi=0;mi<4;++mi){
      int row = wm*64 + mi*16 + cl;
      int key = (row & 7) << 4;
      #pragma unroll
      for (int kk=0;kk<2;++kk)
        af[mi][kk] = *(const short8*)((const char*)As + row*128 + ((kk*64 + cg*16) ^ key));
    }
    #pragma unroll
    for (int ni=0;ni<4;++ni){
      int row = wn*64 + ni*16 + cl;
      int key = (row & 7) << 4;
      #pragma unroll
      for (int kk=0;kk<2;++kk)
        bf[ni][kk] = *(const short8*)((const char*)Bs + row*128 + ((kk*64 + cg*16) ^ key));
    }
    #pragma unroll
    for (int kk=0;kk<2;++kk)
      #pragma unroll
      for (int mi=0;mi<4;++mi)
        #pragma unroll
        for (int ni=0;ni<4;++ni)
          acc[mi][ni] = __builtin_amdgcn_mfma_f32_16x16x32_bf16(af[mi][kk], bf[ni][kk], acc[mi][ni], 0,0,0);
  }

  #pragma unroll
  for (int ni=0;ni<4;++ni){
    int col = n0 + wn*64 + ni*16 + cl;
    float bv = bias[col];
    #pragma unroll
    for (int mi=0;mi<4;++mi){
      int r = m0 + wm*64 + mi*16 + cg*4;
      #pragma unroll
      for (int i=0;i<4;++i){
        float v = acc[mi][ni][i] + bv;
        if (OUT_BF16) ((unsigned short*)Cout)[(size_t)(r+i)*N + col] = f2bf(v);
        else          ((float*)Cout)[(size_t)(r+i)*N + col] = v;
      }
    }
  }
}

// ---------------- fused RMSNorm(q,k) + interleaved RoPE ----------------
__global__ __launch_bounds__(256) void k_norm_rope(unsigned short* __restrict__ qkv,
                                                   const float* __restrict__ fcos,
                                                   const float* __restrict__ fsin,
                                                   const float* __restrict__ gq,
                                                   const float* __restrict__ gk){
  int bl = blockIdx.x;
  int l = bl & (LSEQ-1);
  int t = threadIdx.x;
  unsigned short* row = qkv + (size_t)bl * NQKV;
  int d0 = t*4;
  short4v qv = *(short4v*)(row + d0);
  short4v kv = *(short4v*)(row + DMODEL + d0);
  float q[4], k[4];
  #pragma unroll
  for (int j=0;j<4;++j){ q[j] = bf2f((unsigned short)qv[j]); k[j] = bf2f((unsigned short)kv[j]); }
  float sq = q[0]*q[0]+q[1]*q[1]+q[2]*q[2]+q[3]*q[3];
  float sk = k[0]*k[0]+k[1]*k[1]+k[2]*k[2]+k[3]*k[3];
  #pragma unroll
  for (int o=32;o;o>>=1){ sq += __shfl_xor(sq,o); sk += __shfl_xor(sk,o); }
  __shared__ float red[8];
  int lane = t & 63, wv = t >> 6;
  if (!lane){ red[wv] = sq; red[4+wv] = sk; }
  __syncthreads();
  sq = red[0]+red[1]+red[2]+red[3];
  sk = red[4]+red[5]+red[6]+red[7];
  float rq = rsqrtf(sq*(1.f/1024.f) + 1e-6f);
  float rk = rsqrtf(sk*(1.f/1024.f) + 1e-6f);
  int hd = d0 & (HDIM-1);
  int fi = (l << 6) + (hd >> 1);
  float c0 = fcos[fi], s0 = fsin[fi], c1 = fcos[fi+1], s1 = fsin[fi+1];
  {
    float x1 = q[0]*rq*gq[d0],   x2 = q[1]*rq*gq[d0+1];
    float x3 = q[2]*rq*gq[d0+2], x4 = q[3]*rq*gq[d0+3];
    short4v qo;
    qo[0]=(short)f2bf(x1*c0 - x2*s0); qo[1]=(short)f2bf(x1*s0 + x2*c0);
    qo[2]=(short)f2bf(x3*c1 - x4*s1); qo[3]=(short)f2bf(x3*s1 + x4*c1);
    *(short4v*)(row + d0) = qo;
  }
  {
    float x1 = k[0]*rk*gk[d0],   x2 = k[1]*rk*gk[d0+1];
    float x3 = k[2]*rk*gk[d0+2], x4 = k[3]*rk*gk[d0+3];
    short4v ko;
    ko[0]=(short)f2bf(x1*c0 - x2*s0); ko[1]=(short)f2bf(x1*s0 + x2*c0);
    ko[2]=(short)f2bf(x3*c1 - x4*s1); ko[3]=(short)f2bf(x3*s1 + x4*c1);
    *(short4v*)(row + DMODEL + d0) = ko;
  }
}

// ---------------- flash attention v3: 8 waves x 16 q-rows, swapped QK^T,
// in-register softmax, XOR-swizzled VT + per-wave P LDS bridge (no inline asm) ----
__global__ __launch_bounds__(512, 4) void k_attn(const unsigned short* __restrict__ qkv,
                                                 unsigned short* __restrict__ o){
  __shared__ unsigned short Ks[64*128];      // 16KB, rows 256B, 16B-gran XOR swizzle
  __shared__ unsigned short VT[128*64];      // 16KB, VT[d][kv], 8-elem-gran XOR swizzle
  __shared__ unsigned short Ps[8][16*64];    // 16KB, per-wave P[q][kv], same swizzle
  int bh = blockIdx.y; int b = bh >> 3, h = bh & 7;
  int q0 = blockIdx.x * 128;
  int tid = threadIdx.x, lane = tid & 63, wave = tid >> 6;
  int cg = lane >> 4, cl = lane & 15;
  const unsigned short* base = qkv + (size_t)b*LSEQ*NQKV + h*HDIM;
  const unsigned short* kgl = base + DMODEL;
  const unsigned short* vgl = base + 2*DMODEL;

  // Q fragments (B-operand of swapped QK^T): Q[q=cl][d=kkq*32+cg*8+j]
  short8 qf[4];
  {
    const unsigned short* qr = base + (size_t)(q0 + wave*16 + cl)*NQKV;
    #pragma unroll
    for (int kk=0;kk<4;++kk) qf[kk] = *(const short8*)(qr + kk*32 + cg*8);
  }

  float mrow = -3.0e38f, lrow = 0.f;
  f32x4 zero = {0.f,0.f,0.f,0.f};
  f32x4 accO[8];
  #pragma unroll
  for (int dt=0;dt<8;++dt) accO[dt] = zero;
  const float scale = 0.08838834764831843f;   // 1/sqrt(128)

  // V reg staging: lane = kv row, wave owns d-cols [wave*16, wave*16+16)
  const unsigned short* vsrc = vgl + (size_t)lane*NQKV + wave*16;
  short8 vr0 = *(const short8*)(vsrc);
  short8 vr1 = *(const short8*)(vsrc + 8);

  unsigned short* pw = &Ps[wave][0];
  int keyc = (cl & 7) << 3;    // element-granular XOR key for row cl (and d rows, since dt*16%8==0)

  for (int kv0 = 0; kv0 < LSEQ; kv0 += 64){
    if (kv0) __syncthreads();
    // ---- stage K (2 chunks/wave), pre-swizzled source (R1-proven) ----
    #pragma unroll
    for (int j=0;j<2;++j){
      int ch = wave*2 + j;
      int row = ch*4 + cg;
      int srcb = (cl*16) ^ ((row & 7) << 4);
      gload_lds16(kgl + (size_t)(kv0+row)*NQKV + (srcb >> 1), (char*)Ks + ch*1024);
    }
    // ---- write V regs -> VT[d][kv ^ ((d&7)<<3)] ----
    #pragma unroll
    for (int j=0;j<8;++j){
      int xk = lane ^ (j << 3);
      VT[(wave*16 + j)*64     + xk] = (unsigned short)vr0[j];
      VT[(wave*16 + 8 + j)*64 + xk] = (unsigned short)vr1[j];
    }
    __syncthreads();
    // ---- prefetch next tile's V into regs (latency hides behind compute) ----
    if (kv0 + 64 < LSEQ){
      const unsigned short* vs2 = vsrc + (size_t)(kv0 + 64)*NQKV;
      vr0 = *(const short8*)(vs2);
      vr1 = *(const short8*)(vs2 + 8);
    }

    // ---- QK^T swapped: S^T[kv][q]; lane(cg,cl): kv = nt*16+cg*4+i, q = cl ----
    f32x4 s[4];
    #pragma unroll
    for (int nt=0;nt<4;++nt){
      f32x4 a = zero;
      int row = nt*16 + cl;
      int key = (row & 7) << 4;
      #pragma unroll
      for (int kkq=0;kkq<4;++kkq){
        short8 kf = *(const short8*)((const char*)Ks + row*256 + ((kkq*64 + cg*16) ^ key));
        a = __builtin_amdgcn_mfma_f32_16x16x32_bf16(kf, qf[kkq], a, 0,0,0);
      }
      s[nt] = a;
    }

    // ---- in-register online softmax (per lane: q = cl, 16 kv values) ----
    float mx = s[0][0];
    #pragma unroll
    for (int nt=0;nt<4;++nt)
      #pragma unroll
      for (int i=0;i<4;++i) mx = fmaxf(mx, s[nt][i]);
    mx = fmaxf(mx, __shfl_xor(mx, 16));
    mx = fmaxf(mx, __shfl_xor(mx, 32));
    float mn = fmaxf(mrow, mx * scale);
    float fac = __expf(mrow - mn);
    mrow = mn;
    float sum = 0.f;
    #pragma unroll
    for (int nt=0;nt<4;++nt)
      #pragma unroll
      for (int i=0;i<4;++i){
        float e = __expf(fmaf(s[nt][i], scale, -mn));
        s[nt][i] = e;
        sum += e;
      }
    sum += __shfl_xor(sum, 16);
    sum += __shfl_xor(sum, 32);
    lrow = lrow*fac + sum;
    {
      float fq0 = __shfl(fac, (lane & 48) | (cg*4+0));
      float fq1 = __shfl(fac, (lane & 48) | (cg*4+1));
      float fq2 = __shfl(fac, (lane & 48) | (cg*4+2));
      float fq3 = __shfl(fac, (lane & 48) | (cg*4+3));
      #pragma unroll
      for (int dt=0;dt<8;++dt){
        f32x4 t = accO[dt];
        t[0]*=fq0; t[1]*=fq1; t[2]*=fq2; t[3]*=fq3;
        accO[dt] = t;
      }
    }

    // ---- P bridge: write S^T-layout P to per-wave LDS, read canonical A-frags ----
    #pragma unroll
    for (int nt=0;nt<4;++nt){
      short4v pk;
      pk[0]=(short)f2bf(s[nt][0]); pk[1]=(short)f2bf(s[nt][1]);
      pk[2]=(short)f2bf(s[nt][2]); pk[3]=(short)f2bf(s[nt][3]);
      *(short4v*)&pw[cl*64 + ((nt*16 + cg*4) ^ keyc)] = pk;   // kv = nt*16+cg*4+{0..3}
    }
    short8 pa0 = *(const short8*)&pw[cl*64 + ((cg*8)      ^ keyc)];  // kv = cg*8+e
    short8 pa1 = *(const short8*)&pw[cl*64 + ((32 + cg*8) ^ keyc)];  // kv = 32+cg*8+e

    // ---- PV: O[q][d] += P[q][kv] V[kv][d] ----
    #pragma unroll
    for (int dt=0;dt<8;++dt){
      const unsigned short* vrow = &VT[(dt*16 + cl)*64];
      short8 vf0 = *(const short8*)&vrow[(cg*8)      ^ keyc];
      short8 vf1 = *(const short8*)&vrow[(32 + cg*8) ^ keyc];
      accO[dt] = __builtin_amdgcn_mfma_f32_16x16x32_bf16(pa0, vf0, accO[dt], 0,0,0);
      accO[dt] = __builtin_amdgcn_mfma_f32_16x16x32_bf16(pa1, vf1, accO[dt], 0,0,0);
    }
  }

  // ---- epilogue ----
  float lq0 = __shfl(lrow, (lane & 48) | (cg*4+0));
  float lq1 = __shfl(lrow, (lane & 48) | (cg*4+1));
  float lq2 = __shfl(lrow, (lane & 48) | (cg*4+2));
  float lq3 = __shfl(lrow, (lane & 48) | (cg*4+3));
  float r0 = 1.f/lq0, r1 = 1.f/lq1, r2 = 1.f/lq2, r3 = 1.f/lq3;
  size_t orow = (size_t)(b*LSEQ + q0 + wave*16 + cg*4);
  #pragma unroll
  for (int dt=0;dt<8;++dt){
    int col = h*HDIM + dt*16 + cl;
    o[(orow+0)*DMODEL + col] = f2bf(accO[dt][0]*r0);
    o[(orow+1)*DMODEL + col] = f2bf(accO[dt][1]*r1);
    o[(orow+2)*DMODEL + col] = f2bf(accO[dt][2]*r2);
    o[(orow+3)*DMODEL + col] = f2bf(accO[dt][3]*r3);
  }
}

extern "C" void kernel_launch(void* const* d_in, const int* in_sizes, int n_in,
                              void* d_out, int out_size, void* d_ws, size_t ws_size,
                              hipStream_t stream) {
  const float* x    = (const float*)d_in[0];
  const float* fcos = (const float*)d_in[1];
  const float* fsin = (const float*)d_in[2];
  const float* wqkv = (const float*)d_in[3];
  const float* bqkv = (const float*)d_in[4];
  const float* gq   = (const float*)d_in[5];
  const float* gk   = (const float*)d_in[6];
  const float* wout = (const float*)d_in[7];
  const float* bout = (const float*)d_in[8];
  float* out = (float*)d_out;

  char* ws = (char*)d_ws;
  unsigned short* xb    = (unsigned short*)(ws);                       // 16MB: x bf16
  unsigned short* qkv   = (unsigned short*)(ws + (16ull<<20));         // 48MB: qkv bf16
  unsigned short* ob    = (unsigned short*)(ws + (64ull<<20));         // 16MB: o bf16
  unsigned short* wqkvT = (unsigned short*)(ws + (80ull<<20));         // 6MB
  unsigned short* woutT = (unsigned short*)(ws + (86ull<<20));         // 2MB

  k_cvt<<<4096, 256, 0, stream>>>(x, xb, (MTOT*DMODEL)/8);
  k_transpose_cvt<<<dim3(96,32), 256, 0, stream>>>(wqkv, wqkvT, DMODEL, NQKV);
  k_transpose_cvt<<<dim3(32,32), 256, 0, stream>>>(wout, woutT, DMODEL, DMODEL);
  k_gemm_bt<1><<<dim3(NQKV/128, MTOT/128), 256, 0, stream>>>(xb, wqkvT, bqkv, qkv, MTOT, NQKV, DMODEL);
  k_norm_rope<<<MTOT, 256, 0, stream>>>(qkv, fcos, fsin, gq, gk);
  k_attn<<<dim3(LSEQ/128, 16), 512, 0, stream>>>(qkv, ob);
  k_gemm_bt<0><<<dim3(DMODEL/128, MTOT/128), 256, 0, stream>>>(ob, woutT, bout, out, MTOT, DMODEL, DMODEL);
}